// Round 4
// baseline (1609.608 us; speedup 1.0000x reference)
//
#include <hip/hip_runtime.h>
#include <hip/hip_bf16.h>

// VQ-VAE forward, MFMA implicit-GEMM version.
// Inputs/outputs fp32 (per reference). Intermediates NHWC bf16 in d_ws.
// Conv = 9-tap implicit GEMM: D[oc][pix] += W[oc][ic] * In[pix][ic] per (tap, ic-chunk).
// MFMA 16x16x32 bf16: A[m=lane&15][k=quad*8+j], B[k=quad*8+j][n=lane&15],
//                     D: col(n)=lane&15, row(m)=quad*4+reg   (learn_hip m89/m91/m120).
//
// R4: OCB back to 64 (R0's arithmetic intensity) on top of R3's slim tile.
// Evidence: LDS co-residency pool is 64KB (26KB->2blk, 47KB->1, 21KB->3);
// R3 (OCB=32) doubled staging work and gave back the occupancy gain
// (FETCH 126->222MB, MfmaUtil ~flat). OCB=64 @ 20.7KB LDS + (256,3):
// VGPR ~128 < 170 cap -> still 3 blocks/CU, staging volume halves.

typedef __bf16 bf16x8 __attribute__((ext_vector_type(8)));
typedef float  floatx4 __attribute__((ext_vector_type(4)));

__device__ __forceinline__ unsigned short f2bf(float f) {
    return __builtin_bit_cast(unsigned short, __float2bfloat16(f));
}
__device__ __forceinline__ float bf2f(unsigned short u) {
    return __bfloat162float(__builtin_bit_cast(__hip_bfloat16, u));
}

// ---------------- x: NCHW fp32 -> NHWC bf16, C padded 156->160 -------------
__global__ __launch_bounds__(256) void xpose_k(const float* __restrict__ x,
                                               unsigned short* __restrict__ xn)
{
    __shared__ unsigned short t[64 * 168];   // 64 pixels x 160ch (stride 168)
    const int b = blockIdx.y;
    const int hw0 = blockIdx.x * 64;
    const int cl = threadIdx.x >> 6;         // 0..3
    const int hwl = threadIdx.x & 63;
    #pragma unroll 4
    for (int cc = 0; cc < 40; ++cc) {
        int c = cc * 4 + cl;
        float v = (c < 156) ? x[((size_t)(b * 156 + c) << 14) + hw0 + hwl] : 0.0f;
        t[hwl * 168 + c] = f2bf(v);
    }
    __syncthreads();
    for (int i = threadIdx.x; i < 64 * 20; i += 256) {
        int row = i / 20, qq = i - row * 20;
        uint4 v = *(const uint4*)(t + row * 168 + qq * 8);
        *(uint4*)(xn + ((size_t)((b << 14) + hw0 + row)) * 160 + qq * 8) = v;
    }
}

// ---------------- weight repack: fp32 -> Wrep[tap][oc][ic] bf16 ------------
__global__ __launch_bounds__(256) void repack_k(const float* __restrict__ w,
                                                unsigned short* __restrict__ wr,
                                                int Cout, int Cin, int OCP, int ICP,
                                                int trans, int n)
{
    int i = blockIdx.x * 256 + threadIdx.x;
    if (i >= n) return;
    int ic = i % ICP, rest = i / ICP;
    int oc = rest % OCP, tap = rest / OCP;
    float v = 0.0f;
    if (oc < Cout && ic < Cin) {
        // conv:  w[oc][ic][kh][kw] OIHW;  convT: w_eff[oc][ic][kh][kw]=w[ic][oc][2-kh][2-kw]
        v = trans ? w[(size_t)(ic * Cout + oc) * 9 + (8 - tap)]
                  : w[(size_t)(oc * Cin + ic) * 9 + tap];
    }
    wr[i] = f2bf(v);
}

// ---------------- zero helpers ----------------
__global__ void zero_k(float* p) { *p = 0.0f; }
__global__ __launch_bounds__(256) void zero4_k(uint4* __restrict__ p, int n4)
{
    int i = blockIdx.x * 256 + threadIdx.x;
    if (i < n4) p[i] = uint4{0, 0, 0, 0};
}

// ---------------- MFMA conv ----------------
// ICP: padded in-channels (buffer stride, mult of 32). K-chunk fixed at 32.
// OCB: oc per block (mult 16).
// OMODE 0: NHWC bf16 + relu (OUTC = out buffer C == real Cout)
// OMODE 1: NCHW bf16 + relu, predicate oc<OUTC
// OMODE 2: NCHW fp32 + sigmoid, predicate oc<OUTC
//
// LDS layout: linear [pix p 0..323][4 chunks of 8ch], 16B chunk at byte p*64+m*16.
// Source swizzle: physical chunk m holds k-chunk m ^ s(p), s(p)=(p>>1)&3.
//  - staging writes are linear in thread id -> conflict-free ds_write_b128
//  - reads at byte (p<<6)^(quad<<4)^((p&6)<<3) -> uniform 2-way (free, m136)
template <int ICP, int OCB, int OMODE, int OUTC>
__global__ __launch_bounds__(256, 3) void conv_mfma(const unsigned short* __restrict__ in,
                                                    const unsigned short* __restrict__ wrep,
                                                    const float* __restrict__ bias,
                                                    void* __restrict__ outv, int OCP)
{
    constexpr int NOT = OCB / 16;
    constexpr int NPH = ICP / 32;
    __shared__ unsigned short tile[18 * 18 * 32];   // 20736 B, 3 blocks/CU

    const int tid  = threadIdx.x;
    const int lane = tid & 63, wave = tid >> 6;
    const int col  = lane & 15, quad = lane >> 4;
    const int qsh  = quad << 4;
    const int ocblk = blockIdx.x, tix = blockIdx.y, b = blockIdx.z;
    const int h0 = (tix >> 3) << 4, w0 = (tix & 7) << 4;

    floatx4 acc[NOT][4];
    #pragma unroll
    for (int i = 0; i < NOT; ++i)
        #pragma unroll
        for (int r = 0; r < 4; ++r) acc[i][r] = floatx4{0.f, 0.f, 0.f, 0.f};

    for (int icc = 0; icc < NPH; ++icc) {
        if (icc) __syncthreads();              // tile reuse guard
        // stage 18x18 halo x 32 ic; thread c writes linear chunk c, loads swizzled src chunk
        #pragma unroll
        for (int s = 0; s < 6; ++s) {
            int c = tid + (s << 8);
            if (c < 18 * 18 * 4) {
                int p = c >> 2, m = c & 3;
                int q = m ^ ((p >> 1) & 3);
                int pr = p / 18, pc = p - pr * 18;
                int gh = h0 - 1 + pr, gw = w0 - 1 + pc;
                uint4 v = uint4{0, 0, 0, 0};
                if ((unsigned)gh < 128u && (unsigned)gw < 128u)
                    v = *(const uint4*)(in +
                        (size_t)((((b << 7) + gh) << 7) + gw) * ICP + icc * 32 + (q << 3));
                *(uint4*)(tile + (c << 3)) = v;
            }
        }
        __syncthreads();

        #pragma unroll
        for (int tap = 0; tap < 9; ++tap) {
            const int dh = tap / 3, dw = tap % 3;
            bf16x8 bfr[4];
            #pragma unroll
            for (int rt = 0; rt < 4; ++rt) {
                int p = ((wave << 2) + rt + dh) * 18 + col + dw;
                int boff = (p << 6) ^ qsh ^ ((p & 6) << 3);
                bfr[rt] = *(const bf16x8*)((const char*)tile + boff);
            }
            #pragma unroll
            for (int ot = 0; ot < NOT; ++ot) {
                int oc = ocblk * OCB + (ot << 4) + col;
                const unsigned short* wp =
                    wrep + ((size_t)(tap * OCP + oc)) * ICP + icc * 32 + (quad << 3);
                bf16x8 afr = *(const bf16x8*)wp;
                #pragma unroll
                for (int rt = 0; rt < 4; ++rt)
                    acc[ot][rt] = __builtin_amdgcn_mfma_f32_16x16x32_bf16(
                        afr, bfr[rt], acc[ot][rt], 0, 0, 0);
            }
        }
    }

    // epilogue. D: col=pixel w, row m = quad*4+reg = oc_local
    const int w = w0 + col;
    #pragma unroll
    for (int ot = 0; ot < NOT; ++ot) {
        int oc0 = ocblk * OCB + (ot << 4) + (quad << 2);
        #pragma unroll
        for (int rt = 0; rt < 4; ++rt) {
            int h = h0 + (wave << 2) + rt;
            if constexpr (OMODE == 0) {
                unsigned short* outp = (unsigned short*)outv;
                unsigned short pk[4];
                #pragma unroll
                for (int g = 0; g < 4; ++g) {
                    float vv = acc[ot][rt][g] + bias[oc0 + g];
                    pk[g] = f2bf(fmaxf(vv, 0.0f));
                }
                size_t off = ((size_t)(((b << 7) + h) << 7) + w) * OUTC + oc0;
                *(uint2*)(outp + off) = *(const uint2*)pk;   // 4 consecutive oc, 8B
            } else if constexpr (OMODE == 1) {
                unsigned short* outp = (unsigned short*)outv;
                #pragma unroll
                for (int g = 0; g < 4; ++g) {
                    int oc = oc0 + g;
                    if (oc < OUTC) {
                        float vv = fmaxf(acc[ot][rt][g] + bias[oc], 0.0f);
                        outp[((size_t)(b * OUTC + oc) << 14) + (h << 7) + w] = f2bf(vv);
                    }
                }
            } else {
                float* outp = (float*)outv;
                #pragma unroll
                for (int g = 0; g < 4; ++g) {
                    int oc = oc0 + g;
                    if (oc < OUTC) {
                        float vv = acc[ot][rt][g] + bias[oc];
                        vv = 1.0f / (1.0f + __expf(-vv));
                        outp[((size_t)(b * OUTC + oc) << 14) + (h << 7) + w] = vv;
                    }
                }
            }
        }
    }
}

// ---------------- vector quantizer ----------------
// z3: NCHW bf16 [16,8,128,128]; rows = 8 consecutive flat elements (= 8 w-pixels, one channel).
__global__ __launch_bounds__(256) void vq_k(const unsigned short* __restrict__ z,
                                            const float* __restrict__ emb,
                                            unsigned short* __restrict__ q,
                                            float* __restrict__ loss)
{
    __shared__ float se[512 * 8];
    __shared__ float se2[512];
    __shared__ float red[4];

    for (int i = threadIdx.x; i < 4096; i += 256) se[i] = emb[i];
    __syncthreads();
    for (int k = threadIdx.x; k < 512; k += 256) {
        float s = 0.0f;
        #pragma unroll
        for (int j = 0; j < 8; ++j) { float e = se[k * 8 + j]; s += e * e; }
        se2[k] = s;
    }
    __syncthreads();

    int r = blockIdx.x * 256 + threadIdx.x;   // grid sized exactly 262144
    uint4 raw = *(const uint4*)(z + (size_t)r * 8);
    const unsigned short* pr = (const unsigned short*)&raw;
    float zv[8];
    #pragma unroll
    for (int j = 0; j < 8; ++j) zv[j] = bf2f(pr[j]);

    float best = 3.4e38f;
    int bi = 0;
    for (int k = 0; k < 512; ++k) {
        float dot = 0.0f;
        #pragma unroll
        for (int j = 0; j < 8; ++j) dot += se[k * 8 + j] * zv[j];
        float d = se2[k] - 2.0f * dot;
        if (d < best) { best = d; bi = k; }   // strict <: first-min argmin
    }

    // r = ((b*8+c)*128 + h)*16 + wg
    int wg = r & 15, h = (r >> 4) & 127, c = (r >> 11) & 7, b = r >> 14;
    size_t pixbase = ((size_t)(((b << 7) + h) << 7)) + (wg << 3);
    float lsum = 0.0f;
    #pragma unroll
    for (int j = 0; j < 8; ++j) {
        float e = se[bi * 8 + j];
        q[(pixbase + j) * 32 + c] = f2bf(e);
        float df = e - zv[j];
        lsum += df * df;
    }

    for (int o = 32; o > 0; o >>= 1) lsum += __shfl_down(lsum, o, 64);
    int lane = threadIdx.x & 63, wv = threadIdx.x >> 6;
    if (lane == 0) red[wv] = lsum;
    __syncthreads();
    if (threadIdx.x == 0) atomicAdd(loss, red[0] + red[1] + red[2] + red[3]);
}

__global__ void fin_k(const float* __restrict__ loss, float* __restrict__ out)
{
    out[0] = 1.25f * (*loss) / 2097152.0f;
}

// ---------------- launch ----------------
extern "C" void kernel_launch(void* const* d_in, const int* in_sizes, int n_in,
                              void* d_out, int out_size, void* d_ws, size_t ws_size,
                              hipStream_t stream)
{
    const float* x   = (const float*)d_in[0];
    const float* e1w = (const float*)d_in[1];
    const float* e1b = (const float*)d_in[2];
    const float* e2w = (const float*)d_in[3];
    const float* e2b = (const float*)d_in[4];
    const float* e3w = (const float*)d_in[5];
    const float* e3b = (const float*)d_in[6];
    const float* emb = (const float*)d_in[7];
    const float* d1w = (const float*)d_in[8];
    const float* d1b = (const float*)d_in[9];
    const float* d2w = (const float*)d_in[10];
    const float* d2b = (const float*)d_in[11];
    const float* d3w = (const float*)d_in[12];
    const float* d3b = (const float*)d_in[13];
    float* out = (float*)d_out;

    char* ws = (char*)d_ws;
    size_t off = 0;
    auto alloc = [&](size_t bytes) { void* p = ws + off; off += (bytes + 255) & ~size_t(255); return p; };

    float*          loss  = (float*)alloc(4);
    unsigned short* wr_e1 = (unsigned short*)alloc((size_t)9 * 128 * 160 * 2);
    unsigned short* wr_e2 = (unsigned short*)alloc((size_t)9 * 64 * 128 * 2);
    unsigned short* wr_e3 = (unsigned short*)alloc((size_t)9 * 16 * 64 * 2);
    unsigned short* wr_d1 = (unsigned short*)alloc((size_t)9 * 64 * 32 * 2);
    unsigned short* wr_d2 = (unsigned short*)alloc((size_t)9 * 128 * 64 * 2);
    unsigned short* wr_d3 = (unsigned short*)alloc((size_t)9 * 192 * 128 * 2);
    unsigned short* z3    = (unsigned short*)alloc((size_t)16 * 8 * 16384 * 2);
    unsigned short* qb    = (unsigned short*)alloc((size_t)16 * 16384 * 32 * 2);
    unsigned short* S1    = (unsigned short*)alloc((size_t)16 * 16384 * 160 * 2); // xn -> b2 -> b4
    unsigned short* S2    = (unsigned short*)alloc((size_t)16 * 16384 * 128 * 2); // b1 -> b5
    (void)ws_size;

    zero_k<<<1, 1, 0, stream>>>(loss);
    // zero q (padded 32-ch NHWC; channels 8..31 must be 0)
    zero4_k<<<(16 * 16384 * 32 / 8 + 255) / 256, 256, 0, stream>>>((uint4*)qb, 16 * 16384 * 32 / 8);

    xpose_k<<<dim3(256, 16), 256, 0, stream>>>(x, S1);

    auto rp = [&](const float* w, unsigned short* wr, int Cout, int Cin, int OCP, int ICP, int trans) {
        int n = 9 * OCP * ICP;
        repack_k<<<(n + 255) / 256, 256, 0, stream>>>(w, wr, Cout, Cin, OCP, ICP, trans, n);
    };
    rp(e1w, wr_e1, 128, 156, 128, 160, 0);
    rp(e2w, wr_e2,  64, 128,  64, 128, 0);
    rp(e3w, wr_e3,   8,  64,  16,  64, 0);
    rp(d1w, wr_d1,  64,   8,  64,  32, 1);
    rp(d2w, wr_d2, 128,  64, 128,  64, 1);
    rp(d3w, wr_d3, 156, 128, 192, 128, 1);

    // encoder  (ICP, OCB, OMODE, OUTC); grid.x = OCP/OCB
    conv_mfma<160, 64, 0, 128><<<dim3(2, 64, 16), 256, 0, stream>>>(S1, wr_e1, e1b, S2, 128);
    conv_mfma<128, 64, 0,  64><<<dim3(1, 64, 16), 256, 0, stream>>>(S2, wr_e2, e2b, S1, 64);
    conv_mfma< 64, 16, 1,   8><<<dim3(1, 64, 16), 256, 0, stream>>>(S1, wr_e3, e3b, z3, 16);
    // VQ
    vq_k<<<1024, 256, 0, stream>>>(z3, emb, qb, loss);
    // decoder
    conv_mfma< 32, 64, 0,  64><<<dim3(1, 64, 16), 256, 0, stream>>>(qb, wr_d1, d1b, S1, 64);
    conv_mfma< 64, 64, 0, 128><<<dim3(2, 64, 16), 256, 0, stream>>>(S1, wr_d2, d2b, S2, 128);
    conv_mfma<128, 64, 2, 156><<<dim3(3, 64, 16), 256, 0, stream>>>(S2, wr_d3, d3b, out, 192);

    fin_k<<<1, 1, 0, stream>>>(loss, out + (size_t)16 * 156 * 16384);
}

// Round 5
// 1049.160 us; speedup vs baseline: 1.5342x; 1.5342x over previous
//
#include <hip/hip_runtime.h>
#include <hip/hip_bf16.h>

// VQ-VAE forward, MFMA implicit-GEMM version.
// Inputs/outputs fp32 (per reference). Intermediates NHWC bf16 in d_ws.
// Conv = 9-tap implicit GEMM: D[oc][pix] += W[oc][ic] * In[pix][ic] per (tap, ic-chunk).
// MFMA 16x16x32 bf16: A[m=lane&15][k=quad*8+j], B[k=quad*8+j][n=lane&15],
//                     D: col(n)=lane&15, row(m)=quad*4+reg   (learn_hip m89/m91/m120).
//
// R5: latency-hiding at fixed 2 blocks/CU.
//  - R4 lesson: (256,3) + OCB=64 spills acc (VGPR 128->84, FETCH+WRITE +580MB scratch).
//    -> __launch_bounds__(256,2): cap 256 regs; LDS (20.7KB) limits to 2 blocks anyway.
//  - Weight loads batched per tap (all NOT afr issued before MFMAs).
//  - T14 stage split: next phase's 6 global loads issued before compute, committed after.

typedef __bf16 bf16x8 __attribute__((ext_vector_type(8)));
typedef float  floatx4 __attribute__((ext_vector_type(4)));

__device__ __forceinline__ unsigned short f2bf(float f) {
    return __builtin_bit_cast(unsigned short, __float2bfloat16(f));
}
__device__ __forceinline__ float bf2f(unsigned short u) {
    return __bfloat162float(__builtin_bit_cast(__hip_bfloat16, u));
}

// ---------------- x: NCHW fp32 -> NHWC bf16, C padded 156->160 -------------
__global__ __launch_bounds__(256) void xpose_k(const float* __restrict__ x,
                                               unsigned short* __restrict__ xn)
{
    __shared__ unsigned short t[64 * 168];   // 64 pixels x 160ch (stride 168)
    const int b = blockIdx.y;
    const int hw0 = blockIdx.x * 64;
    const int cl = threadIdx.x >> 6;         // 0..3
    const int hwl = threadIdx.x & 63;
    #pragma unroll 4
    for (int cc = 0; cc < 40; ++cc) {
        int c = cc * 4 + cl;
        float v = (c < 156) ? x[((size_t)(b * 156 + c) << 14) + hw0 + hwl] : 0.0f;
        t[hwl * 168 + c] = f2bf(v);
    }
    __syncthreads();
    for (int i = threadIdx.x; i < 64 * 20; i += 256) {
        int row = i / 20, qq = i - row * 20;
        uint4 v = *(const uint4*)(t + row * 168 + qq * 8);
        *(uint4*)(xn + ((size_t)((b << 14) + hw0 + row)) * 160 + qq * 8) = v;
    }
}

// ---------------- weight repack: fp32 -> Wrep[tap][oc][ic] bf16 ------------
__global__ __launch_bounds__(256) void repack_k(const float* __restrict__ w,
                                                unsigned short* __restrict__ wr,
                                                int Cout, int Cin, int OCP, int ICP,
                                                int trans, int n)
{
    int i = blockIdx.x * 256 + threadIdx.x;
    if (i >= n) return;
    int ic = i % ICP, rest = i / ICP;
    int oc = rest % OCP, tap = rest / OCP;
    float v = 0.0f;
    if (oc < Cout && ic < Cin) {
        // conv:  w[oc][ic][kh][kw] OIHW;  convT: w_eff[oc][ic][kh][kw]=w[ic][oc][2-kh][2-kw]
        v = trans ? w[(size_t)(ic * Cout + oc) * 9 + (8 - tap)]
                  : w[(size_t)(oc * Cin + ic) * 9 + tap];
    }
    wr[i] = f2bf(v);
}

// ---------------- zero helpers ----------------
__global__ void zero_k(float* p) { *p = 0.0f; }
__global__ __launch_bounds__(256) void zero4_k(uint4* __restrict__ p, int n4)
{
    int i = blockIdx.x * 256 + threadIdx.x;
    if (i < n4) p[i] = uint4{0, 0, 0, 0};
}

// ---------------- MFMA conv ----------------
// ICP: padded in-channels (buffer stride, mult of 32). K-chunk fixed at 32.
// OCB: oc per block (mult 16).
// OMODE 0: NHWC bf16 + relu (OUTC = out buffer C == real Cout)
// OMODE 1: NCHW bf16 + relu, predicate oc<OUTC
// OMODE 2: NCHW fp32 + sigmoid, predicate oc<OUTC
//
// LDS layout: linear [pix p 0..323][4 chunks of 8ch], 16B chunk at byte p*64+m*16.
// Source swizzle: physical chunk m holds k-chunk m ^ s(p), s(p)=(p>>1)&3.
//  - staging writes are linear in thread id -> conflict-free ds_write_b128
//  - reads at byte (p<<6)^(quad<<4)^((p&6)<<3) -> uniform 2-way (free, m136)
template <int ICP, int OCB, int OMODE, int OUTC>
__global__ __launch_bounds__(256, 2) void conv_mfma(const unsigned short* __restrict__ in,
                                                    const unsigned short* __restrict__ wrep,
                                                    const float* __restrict__ bias,
                                                    void* __restrict__ outv, int OCP)
{
    constexpr int NOT = OCB / 16;
    constexpr int NPH = ICP / 32;
    __shared__ unsigned short tile[18 * 18 * 32];   // 20736 B

    const int tid  = threadIdx.x;
    const int lane = tid & 63, wave = tid >> 6;
    const int col  = lane & 15, quad = lane >> 4;
    const int qsh  = quad << 4;
    const int ocblk = blockIdx.x, tix = blockIdx.y, b = blockIdx.z;
    const int h0 = (tix >> 3) << 4, w0 = (tix & 7) << 4;

    floatx4 acc[NOT][4];
    #pragma unroll
    for (int i = 0; i < NOT; ++i)
        #pragma unroll
        for (int r = 0; r < 4; ++r) acc[i][r] = floatx4{0.f, 0.f, 0.f, 0.f};

    // ---- per-thread staging descriptors (base element offset at icc=0, or -1) ----
    int goffv[6];
    #pragma unroll
    for (int s = 0; s < 6; ++s) {
        int c = tid + (s << 8);
        int p = c >> 2, m = c & 3;
        int q = m ^ ((p >> 1) & 3);           // source-side swizzle (rule #21 pair)
        int pr = p / 18, pc = p - pr * 18;
        int gh = h0 - 1 + pr, gw = w0 - 1 + pc;
        bool ok = (c < 18 * 18 * 4) && ((unsigned)gh < 128u) && ((unsigned)gw < 128u);
        goffv[s] = ok ? ((((b << 7) + gh) << 7) + gw) * ICP + (q << 3) : -1;
    }

    uint4 v[6];
    auto load_ph = [&](int icc) {
        #pragma unroll
        for (int s = 0; s < 6; ++s) {
            v[s] = uint4{0, 0, 0, 0};
            if (goffv[s] >= 0)
                v[s] = *(const uint4*)(in + (size_t)goffv[s] + icc * 32);
        }
    };
    auto store_ph = [&]() {
        #pragma unroll
        for (int s = 0; s < 6; ++s) {
            int c = tid + (s << 8);
            if (c < 18 * 18 * 4) *(uint4*)(tile + (c << 3)) = v[s];
        }
    };
    auto compute_ph = [&](int icc) {
        #pragma unroll
        for (int tap = 0; tap < 9; ++tap) {
            const int dh = tap / 3, dw = tap % 3;
            // batch ALL weight loads for this tap before any use (one wait, not NOT)
            bf16x8 afr[NOT];
            #pragma unroll
            for (int ot = 0; ot < NOT; ++ot) {
                int oc = ocblk * OCB + (ot << 4) + col;
                afr[ot] = *(const bf16x8*)(wrep +
                    ((size_t)(tap * OCP + oc)) * ICP + icc * 32 + (quad << 3));
            }
            bf16x8 bfr[4];
            #pragma unroll
            for (int rt = 0; rt < 4; ++rt) {
                int p = ((wave << 2) + rt + dh) * 18 + col + dw;
                int boff = (p << 6) ^ qsh ^ ((p & 6) << 3);
                bfr[rt] = *(const bf16x8*)((const char*)tile + boff);
            }
            #pragma unroll
            for (int ot = 0; ot < NOT; ++ot)
                #pragma unroll
                for (int rt = 0; rt < 4; ++rt)
                    acc[ot][rt] = __builtin_amdgcn_mfma_f32_16x16x32_bf16(
                        afr[ot], bfr[rt], acc[ot][rt], 0, 0, 0);
        }
    };

    // ---- pipeline: load(0); store; sync; { prefetch(i+1); compute(i); sync; store; sync } ----
    load_ph(0);
    store_ph();
    __syncthreads();
    #pragma unroll
    for (int icc = 0; icc < NPH; ++icc) {
        if (icc + 1 < NPH) load_ph(icc + 1);    // T14: issue early,
        compute_ph(icc);                        //      HBM latency hides under MFMAs
        if (icc + 1 < NPH) {
            __syncthreads();                    // all tile reads done
            store_ph();                         // commit late
            __syncthreads();
        }
    }

    // epilogue. D: col=pixel w, row m = quad*4+reg = oc_local
    const int w = w0 + col;
    #pragma unroll
    for (int ot = 0; ot < NOT; ++ot) {
        int oc0 = ocblk * OCB + (ot << 4) + (quad << 2);
        #pragma unroll
        for (int rt = 0; rt < 4; ++rt) {
            int h = h0 + (wave << 2) + rt;
            if constexpr (OMODE == 0) {
                unsigned short* outp = (unsigned short*)outv;
                unsigned short pk[4];
                #pragma unroll
                for (int g = 0; g < 4; ++g) {
                    float vv = acc[ot][rt][g] + bias[oc0 + g];
                    pk[g] = f2bf(fmaxf(vv, 0.0f));
                }
                size_t off = ((size_t)(((b << 7) + h) << 7) + w) * OUTC + oc0;
                *(uint2*)(outp + off) = *(const uint2*)pk;   // 4 consecutive oc, 8B
            } else if constexpr (OMODE == 1) {
                unsigned short* outp = (unsigned short*)outv;
                #pragma unroll
                for (int g = 0; g < 4; ++g) {
                    int oc = oc0 + g;
                    if (oc < OUTC) {
                        float vv = fmaxf(acc[ot][rt][g] + bias[oc], 0.0f);
                        outp[((size_t)(b * OUTC + oc) << 14) + (h << 7) + w] = f2bf(vv);
                    }
                }
            } else {
                float* outp = (float*)outv;
                #pragma unroll
                for (int g = 0; g < 4; ++g) {
                    int oc = oc0 + g;
                    if (oc < OUTC) {
                        float vv = acc[ot][rt][g] + bias[oc];
                        vv = 1.0f / (1.0f + __expf(-vv));
                        outp[((size_t)(b * OUTC + oc) << 14) + (h << 7) + w] = vv;
                    }
                }
            }
        }
    }
}

// ---------------- vector quantizer ----------------
// z3: NCHW bf16 [16,8,128,128]; rows = 8 consecutive flat elements (= 8 w-pixels, one channel).
__global__ __launch_bounds__(256) void vq_k(const unsigned short* __restrict__ z,
                                            const float* __restrict__ emb,
                                            unsigned short* __restrict__ q,
                                            float* __restrict__ loss)
{
    __shared__ float se[512 * 8];
    __shared__ float se2[512];
    __shared__ float red[4];

    for (int i = threadIdx.x; i < 4096; i += 256) se[i] = emb[i];
    __syncthreads();
    for (int k = threadIdx.x; k < 512; k += 256) {
        float s = 0.0f;
        #pragma unroll
        for (int j = 0; j < 8; ++j) { float e = se[k * 8 + j]; s += e * e; }
        se2[k] = s;
    }
    __syncthreads();

    int r = blockIdx.x * 256 + threadIdx.x;   // grid sized exactly 262144
    uint4 raw = *(const uint4*)(z + (size_t)r * 8);
    const unsigned short* pr = (const unsigned short*)&raw;
    float zv[8];
    #pragma unroll
    for (int j = 0; j < 8; ++j) zv[j] = bf2f(pr[j]);

    float best = 3.4e38f;
    int bi = 0;
    for (int k = 0; k < 512; ++k) {
        float dot = 0.0f;
        #pragma unroll
        for (int j = 0; j < 8; ++j) dot += se[k * 8 + j] * zv[j];
        float d = se2[k] - 2.0f * dot;
        if (d < best) { best = d; bi = k; }   // strict <: first-min argmin
    }

    // r = ((b*8+c)*128 + h)*16 + wg
    int wg = r & 15, h = (r >> 4) & 127, c = (r >> 11) & 7, b = r >> 14;
    size_t pixbase = ((size_t)(((b << 7) + h) << 7)) + (wg << 3);
    float lsum = 0.0f;
    #pragma unroll
    for (int j = 0; j < 8; ++j) {
        float e = se[bi * 8 + j];
        q[(pixbase + j) * 32 + c] = f2bf(e);
        float df = e - zv[j];
        lsum += df * df;
    }

    for (int o = 32; o > 0; o >>= 1) lsum += __shfl_down(lsum, o, 64);
    int lane = threadIdx.x & 63, wv = threadIdx.x >> 6;
    if (lane == 0) red[wv] = lsum;
    __syncthreads();
    if (threadIdx.x == 0) atomicAdd(loss, red[0] + red[1] + red[2] + red[3]);
}

__global__ void fin_k(const float* __restrict__ loss, float* __restrict__ out)
{
    out[0] = 1.25f * (*loss) / 2097152.0f;
}

// ---------------- launch ----------------
extern "C" void kernel_launch(void* const* d_in, const int* in_sizes, int n_in,
                              void* d_out, int out_size, void* d_ws, size_t ws_size,
                              hipStream_t stream)
{
    const float* x   = (const float*)d_in[0];
    const float* e1w = (const float*)d_in[1];
    const float* e1b = (const float*)d_in[2];
    const float* e2w = (const float*)d_in[3];
    const float* e2b = (const float*)d_in[4];
    const float* e3w = (const float*)d_in[5];
    const float* e3b = (const float*)d_in[6];
    const float* emb = (const float*)d_in[7];
    const float* d1w = (const float*)d_in[8];
    const float* d1b = (const float*)d_in[9];
    const float* d2w = (const float*)d_in[10];
    const float* d2b = (const float*)d_in[11];
    const float* d3w = (const float*)d_in[12];
    const float* d3b = (const float*)d_in[13];
    float* out = (float*)d_out;

    char* ws = (char*)d_ws;
    size_t off = 0;
    auto alloc = [&](size_t bytes) { void* p = ws + off; off += (bytes + 255) & ~size_t(255); return p; };

    float*          loss  = (float*)alloc(4);
    unsigned short* wr_e1 = (unsigned short*)alloc((size_t)9 * 128 * 160 * 2);
    unsigned short* wr_e2 = (unsigned short*)alloc((size_t)9 * 64 * 128 * 2);
    unsigned short* wr_e3 = (unsigned short*)alloc((size_t)9 * 16 * 64 * 2);
    unsigned short* wr_d1 = (unsigned short*)alloc((size_t)9 * 64 * 32 * 2);
    unsigned short* wr_d2 = (unsigned short*)alloc((size_t)9 * 128 * 64 * 2);
    unsigned short* wr_d3 = (unsigned short*)alloc((size_t)9 * 192 * 128 * 2);
    unsigned short* z3    = (unsigned short*)alloc((size_t)16 * 8 * 16384 * 2);
    unsigned short* qb    = (unsigned short*)alloc((size_t)16 * 16384 * 32 * 2);
    unsigned short* S1    = (unsigned short*)alloc((size_t)16 * 16384 * 160 * 2); // xn -> b2 -> b4
    unsigned short* S2    = (unsigned short*)alloc((size_t)16 * 16384 * 128 * 2); // b1 -> b5
    (void)ws_size;

    zero_k<<<1, 1, 0, stream>>>(loss);
    // zero q (padded 32-ch NHWC; channels 8..31 must be 0)
    zero4_k<<<(16 * 16384 * 32 / 8 + 255) / 256, 256, 0, stream>>>((uint4*)qb, 16 * 16384 * 32 / 8);

    xpose_k<<<dim3(256, 16), 256, 0, stream>>>(x, S1);

    auto rp = [&](const float* w, unsigned short* wr, int Cout, int Cin, int OCP, int ICP, int trans) {
        int n = 9 * OCP * ICP;
        repack_k<<<(n + 255) / 256, 256, 0, stream>>>(w, wr, Cout, Cin, OCP, ICP, trans, n);
    };
    rp(e1w, wr_e1, 128, 156, 128, 160, 0);
    rp(e2w, wr_e2,  64, 128,  64, 128, 0);
    rp(e3w, wr_e3,   8,  64,  16,  64, 0);
    rp(d1w, wr_d1,  64,   8,  64,  32, 1);
    rp(d2w, wr_d2, 128,  64, 128,  64, 1);
    rp(d3w, wr_d3, 156, 128, 192, 128, 1);

    // encoder  (ICP, OCB, OMODE, OUTC); grid.x = OCP/OCB
    conv_mfma<160, 64, 0, 128><<<dim3(2, 64, 16), 256, 0, stream>>>(S1, wr_e1, e1b, S2, 128);
    conv_mfma<128, 64, 0,  64><<<dim3(1, 64, 16), 256, 0, stream>>>(S2, wr_e2, e2b, S1, 64);
    conv_mfma< 64, 16, 1,   8><<<dim3(1, 64, 16), 256, 0, stream>>>(S1, wr_e3, e3b, z3, 16);
    // VQ
    vq_k<<<1024, 256, 0, stream>>>(z3, emb, qb, loss);
    // decoder
    conv_mfma< 32, 64, 0,  64><<<dim3(1, 64, 16), 256, 0, stream>>>(qb, wr_d1, d1b, S1, 64);
    conv_mfma< 64, 64, 0, 128><<<dim3(2, 64, 16), 256, 0, stream>>>(S1, wr_d2, d2b, S2, 128);
    conv_mfma<128, 64, 2, 156><<<dim3(3, 64, 16), 256, 0, stream>>>(S2, wr_d3, d3b, out, 192);

    fin_k<<<1, 1, 0, stream>>>(loss, out + (size_t)16 * 156 * 16384);
}